// Round 1
// baseline (138.605 us; speedup 1.0000x reference)
//
#include <hip/hip_runtime.h>
#include <math.h>

// Problem constants (from reference)
#define NCLS   100
#define BATCH_ 2048
#define NPAIR  1024
#define OK     9        // POLICY_NUMS + 2
#define FHALF  64       // FEATURE_NUMS / 2

// Workspace accumulator layout (floats):
// [0] ce_sum  (sum over rows of logZ - x[label])
// [1] kl_sum  (sum over rows of KL@T4 row term)
// [2 + k*8 + {0..7}] : D1u,D2u,D1w,D2w,U1,U2,Wa1,Wa2  for k=0..8   (ends at 74)
// [74 +   0.. 79] cnt1[8][10]   (histogram of t1 = targets rows 0::2, col c)
// [74 +  80..159] cnt2[8][10]   (histogram of t2 = targets rows 1::2, col c)
// [74 + 160..239] sA[8][10]     (sum of As[:, c+1] bucketed by t1[:,c])
// [74 + 240..319] sB[8][10]     (sum of Bs[:, c+1] bucketed by t2[:,c])
#define ACC_FLOATS 394

__device__ __forceinline__ float waveSum(float v) {
#pragma unroll
    for (int off = 32; off; off >>= 1) v += __shfl_xor(v, off, 64);
    return v;
}
__device__ __forceinline__ float waveMax(float v) {
#pragma unroll
    for (int off = 32; off; off >>= 1) v = fmaxf(v, __shfl_xor(v, off, 64));
    return v;
}

__global__ __launch_bounds__(256) void main_kernel(
        const float* __restrict__ slog, const float* __restrict__ tlog,
        const float* __restrict__ spol, const float* __restrict__ tpol,
        const float* __restrict__ W1,   const float* __restrict__ W2,
        const int*   __restrict__ tgt,  float* __restrict__ acc)
{
    __shared__ float w1s[OK * 128];
    __shared__ float w2s[OK * 128];
    __shared__ float bkt[320];
    const int tid = threadIdx.x;

    if (blockIdx.x < 32) {
        // ---------------- logits: CE + KL(T=4), one wave per row ----------------
        const int wid  = blockIdx.x * 4 + (tid >> 6);   // 0..127
        const int lane = tid & 63;
        float ce_l = 0.f, kl_l = 0.f;
        for (int r = wid; r < BATCH_; r += 128) {
            const float* x = slog + r * NCLS;
            const float* y = tlog + r * NCLS;
            const bool has2 = lane < (NCLS - 64);
            float x1 = x[lane];
            float y1 = y[lane];
            float x2 = has2 ? x[lane + 64] : -3.0e38f;
            float y2 = has2 ? y[lane + 64] : -3.0e38f;
            float mx = waveMax(fmaxf(x1, x2));
            float my = waveMax(fmaxf(y1, y2));
            float se1  = waveSum(expf(x1 - mx) + (has2 ? expf(x2 - mx) : 0.f));
            float se4s = waveSum(expf((x1 - mx) * 0.25f) + (has2 ? expf((x2 - mx) * 0.25f) : 0.f));
            float e1 = expf((y1 - my) * 0.25f);
            float e2 = has2 ? expf((y2 - my) * 0.25f) : 0.f;
            float se4t = waveSum(e1 + e2);
            float tnum = waveSum(e1 * (y1 - x1) * 0.25f + (has2 ? e2 * (y2 - x2) * 0.25f : 0.f));
            if (lane == 0) {
                float logZ1 = mx + logf(se1);
                int label = tgt[r * 8];                 // targets[:, 0, 0]
                ce_l += logZ1 - x[label];
                float logZ4s = mx * 0.25f + logf(se4s);
                float logZ4t = my * 0.25f + logf(se4t);
                kl_l += tnum / se4t + logZ4s - logZ4t;  // sum_c tprob*(tlogp - slogp)
            }
        }
        if ((tid & 63) == 0) {
            atomicAdd(&acc[0], ce_l);
            atomicAdd(&acc[1], kl_l);
        }
    } else {
        // ---------------- policy: pair-linear closed-form stats ----------------
        for (int idx = tid; idx < OK * 128; idx += 256) { w1s[idx] = W1[idx]; w2s[idx] = W2[idx]; }
        for (int idx = tid; idx < 320; idx += 256) bkt[idx] = 0.f;
        __syncthreads();

        const int i = (blockIdx.x - 32) * 256 + tid;    // pair-row 0..1023
        const float* f1s = spol + (2 * i) * FHALF;      // A-side (even rows)
        const float* f2s = spol + (2 * i + 1) * FHALF;  // B-side (odd rows)
        const float* f1t = tpol + (2 * i) * FHALF;
        const float* f2t = tpol + (2 * i + 1) * FHALF;

        float As[OK], Bs[OK], At[OK], Bt[OK];
#pragma unroll
        for (int k = 0; k < OK; ++k) { As[k] = 0.f; Bs[k] = 0.f; At[k] = 0.f; Bt[k] = 0.f; }
        for (int f = 0; f < FHALF; ++f) {
            float a = f1s[f], b = f2s[f], c = f1t[f], d = f2t[f];
#pragma unroll
            for (int k = 0; k < OK; ++k) {
                As[k] = fmaf(a, w2s[k * 128 + f],      As[k]);   // A_s[i,k] = f1 . W2[k,:64]
                Bs[k] = fmaf(b, w2s[k * 128 + 64 + f], Bs[k]);   // B_s[i,k] = f2 . W2[k,64:]
                At[k] = fmaf(c, w1s[k * 128 + f],      At[k]);
                Bt[k] = fmaf(d, w1s[k * 128 + 64 + f], Bt[k]);
            }
        }

        // per-k reductions (no bias folded in; combine handles bias terms)
#pragma unroll
        for (int k = 0; k < OK; ++k) {
            float du = Bs[k] - Bt[k], dw = As[k] - At[k];
            float s0 = waveSum(du),        s1 = waveSum(du * du);
            float s2 = waveSum(dw),        s3 = waveSum(dw * dw);
            float s4 = waveSum(Bs[k]),     s5 = waveSum(Bs[k] * Bs[k]);
            float s6 = waveSum(As[k]),     s7 = waveSum(As[k] * As[k]);
            if ((tid & 63) == 0) {
                float* p = acc + 2 + k * 8;
                atomicAdd(p + 0, s0); atomicAdd(p + 1, s1);
                atomicAdd(p + 2, s2); atomicAdd(p + 3, s3);
                atomicAdd(p + 4, s4); atomicAdd(p + 5, s5);
                atomicAdd(p + 6, s6); atomicAdd(p + 7, s7);
            }
        }

        // target-value buckets (10 values, 8 columns)
        const int* t1r = tgt + (2 * i) * 8;
        const int* t2r = tgt + (2 * i + 1) * 8;
#pragma unroll
        for (int c0 = 0; c0 < 8; ++c0) {
            int v1 = t1r[c0], v2 = t2r[c0];
            atomicAdd(&bkt[0 * 80 + c0 * 10 + v1], 1.0f);
            atomicAdd(&bkt[1 * 80 + c0 * 10 + v2], 1.0f);
            atomicAdd(&bkt[2 * 80 + c0 * 10 + v1], As[c0 + 1]);
            atomicAdd(&bkt[3 * 80 + c0 * 10 + v2], Bs[c0 + 1]);
        }
        __syncthreads();
        for (int idx = tid; idx < 320; idx += 256) atomicAdd(&acc[74 + idx], bkt[idx]);
    }
}

__global__ void combine_kernel(const float* __restrict__ acc,
                               const float* __restrict__ bias1,
                               const float* __restrict__ bias2,
                               float* __restrict__ out)
{
    if (threadIdx.x != 0 || blockIdx.x != 0) return;
    const double N = 1024.0, M = 1048576.0;

    double ce_main = (double)acc[0] / (double)BATCH_;
    double kl_main = (double)acc[1] * 16.0 / (double)(BATCH_ * NCLS);

    double kl_pol = 0.0, Sp_acc = 0.0;
    double SumL[OK], SumL2[OK];
    for (int k = 0; k < OK; ++k) {
        const float* p = acc + 2 + k * 8;
        double D1u = p[0], D2u = p[1], D1w = p[2], D2w = p[3];
        double U1 = p[4], U2 = p[5], Wa1 = p[6], Wa2 = p[7];
        double cd = (double)bias2[k] - (double)bias1[k];
        double b  = (double)bias2[k];
        // sum_{i,j} (du_i + dw_j + cd)^2
        double S = N * D2u + N * (D2w + 2.0 * cd * D1w + N * cd * cd)
                 + 2.0 * D1u * (D1w + N * cd);
        if (k == 0)      kl_pol += S / M;            // POS_W[0]=NEG_W[0]=1.0
        else if (k == 1) kl_pol += 0.5 * S / M;      // 0.5
        else             Sp_acc += S;                // 0.001 / 7 applied below
        // student-only sums (bias folded): sum sL, sum sL^2
        SumL[k]  = N * U1 + N * Wa1 + M * b;
        SumL2[k] = N * U2 + N * (Wa2 + 2.0 * b * Wa1 + N * b * b)
                 + 2.0 * U1 * (Wa1 + N * b);
    }
    kl_pol += 0.001 * Sp_acc / (7.0 * M);

    // ce identity term: -(1/M) * sum_i sI[i,i]
    double U1_0 = (double)acc[2 + 0 * 8 + 4], W1_0 = (double)acc[2 + 0 * 8 + 6];
    double ce_I = -(U1_0 + W1_0 + N * (double)bias2[0]) / M;

    const float* cnt1 = acc + 74;
    const float* cnt2 = acc + 74 + 80;
    const float* sA   = acc + 74 + 160;
    const float* sB   = acc + 74 + 240;
    double ce_C = 0.0, ceP = 0.0;
    for (int c0 = 0; c0 < 8; ++c0) {
        double ms = 0.0, pc = 0.0;
        for (int v = 0; v < 10; ++v) {
            double c1 = (double)cnt1[c0 * 10 + v], c2 = (double)cnt2[c0 * 10 + v];
            ms += c1 * (double)sB[c0 * 10 + v] + c2 * (double)sA[c0 * 10 + v];
            pc += c1 * c2;
        }
        ms += (double)bias2[c0 + 1] * pc;   // sum over matching pairs of sL[.,.,c0+1]
        if (c0 == 0) {
            ce_C = -0.5 * ms / M;           // 0.5 * kldiv(sC, gC)
        } else {
            int k = c0 + 1;
            double sg = 2.0 * ms - SumL[k]; // sum sP*gP
            ceP += SumL2[k] - 2.0 * sg + M; // sum (sP - gP)^2, gP^2 = 1
        }
    }
    ceP *= 0.001 / (7.0 * M);

    double policy = kl_pol + ce_I + ce_C + ceP;
    out[0] = (float)(ce_main + kl_main + policy);
}

extern "C" void kernel_launch(void* const* d_in, const int* in_sizes, int n_in,
                              void* d_out, int out_size, void* d_ws, size_t ws_size,
                              hipStream_t stream) {
    const float* slog = (const float*)d_in[0];
    const float* tlog = (const float*)d_in[1];
    const float* spol = (const float*)d_in[2];
    const float* tpol = (const float*)d_in[3];
    const float* W1   = (const float*)d_in[4];
    const float* b1   = (const float*)d_in[5];
    const float* W2   = (const float*)d_in[6];
    const float* b2   = (const float*)d_in[7];
    const int*   tgt  = (const int*)d_in[8];
    float* acc = (float*)d_ws;

    hipMemsetAsync(acc, 0, ACC_FLOATS * sizeof(float), stream);
    main_kernel<<<36, 256, 0, stream>>>(slog, tlog, spol, tpol, W1, W2, tgt, acc);
    combine_kernel<<<1, 64, 0, stream>>>(acc, b1, b2, (float*)d_out);
}